// Round 6
// baseline (165.529 us; speedup 1.0000x reference)
//
#include <hip/hip_runtime.h>
#include <cstdint>

#define DEV __device__ __forceinline__

using short8   = __attribute__((ext_vector_type(8))) short;
using floatx4  = __attribute__((ext_vector_type(4))) float;
using ushortx4 = __attribute__((ext_vector_type(4))) unsigned short;
using intx4    = __attribute__((ext_vector_type(4))) int;

#define MFMA_BF16(a, b, c) __builtin_amdgcn_mfma_f32_16x16x32_bf16((a), (b), (c), 0, 0, 0)

// 1/sqrt(64) * log2(e): fold softmax scale + exp2 conversion into Q
static constexpr float QK_SCALE_LOG2E = 0.18033688011112042f;

DEV unsigned short f2bf(float f) {
  unsigned int u = __builtin_bit_cast(unsigned int, f);
  u += 0x7FFFu + ((u >> 16) & 1u);  // RNE
  return (unsigned short)(u >> 16);
}

DEV int cvt_pk_bf16(float lo, float hi) {
  int r;
  asm("v_cvt_pk_bf16_f32 %0, %1, %2" : "=v"(r) : "v"(lo), "v"(hi));
  return r;
}

DEV void gload_lds16(const void* g, void* l) {
  __builtin_amdgcn_global_load_lds(
      (const __attribute__((address_space(1))) void*)g,
      (__attribute__((address_space(3))) void*)l, 16, 0, 0);
}

// ---------------- fp32 -> bf16 bulk converts ----------------
__global__ void cvt_f32_bf16(const float* __restrict__ src,
                             unsigned short* __restrict__ dst, int n4) {
  int i = blockIdx.x * blockDim.x + threadIdx.x;
  if (i >= n4) return;
  float4 v = reinterpret_cast<const float4*>(src)[i];
  ushortx4 o = {f2bf(v.x), f2bf(v.y), f2bf(v.z), f2bf(v.w)};
  reinterpret_cast<ushortx4*>(dst)[i] = o;
}

// 4 weight matrices (1024x1024 f32 each) -> contiguous bf16 dst
__global__ void cvt_w4(const float* __restrict__ w0, const float* __restrict__ w1,
                       const float* __restrict__ w2, const float* __restrict__ w3,
                       unsigned short* __restrict__ dst) {
  int i = blockIdx.x * blockDim.x + threadIdx.x;  // [0, 4*262144) float4 units
  int b = i >> 18;                                 // wave-uniform (256K per buffer)
  const float* src = (b == 0) ? w0 : (b == 1) ? w1 : (b == 2) ? w2 : w3;
  int off = i & 0x3FFFF;
  float4 v = reinterpret_cast<const float4*>(src)[off];
  ushortx4 o = {f2bf(v.x), f2bf(v.y), f2bf(v.z), f2bf(v.w)};
  reinterpret_cast<ushortx4*>(dst)[i] = o;
}

// ---- staging: global -> LDS, linear LDS dest, swizzle applied on SOURCE ----
// 128 rows x 64 bf16 cols (128B rows, 8x16B chunks), swizzle chunk^(row&7)
DEV void stage128x64(const unsigned short* gbase, int ld, unsigned short* lds, int tid) {
#pragma unroll
  for (int j = 0; j < 4; ++j) {
    int s = j * 256 + tid;
    int row = s >> 3, slot = s & 7;
    int chunk = slot ^ (row & 7);
    gload_lds16(gbase + row * ld + chunk * 8, (char*)lds + s * 16);
  }
}

// 64 rows x 64 bf16 cols. KMODE 1: mask=(row&3)|((row>>1)&4) (K tile, matches
// tau-permuted fragment reads); KMODE 0: mask=row&7 (V tile, consecutive rows).
template <int KMODE>
DEV void stage64x64(const unsigned short* gbase, int ld, unsigned short* lds, int tid) {
#pragma unroll
  for (int j = 0; j < 2; ++j) {
    int s = j * 256 + tid;
    int row = s >> 3, slot = s & 7;
    int mask = KMODE ? ((row & 3) | ((row >> 1) & 4)) : (row & 7);
    int chunk = slot ^ mask;
    gload_lds16(gbase + row * ld + chunk * 8, (char*)lds + s * 16);
  }
}

// ---------------- fused QKV GEMM ----------------
// A [8192][1024] bf16, Wqkv = 3 contiguous [1024][1024] bf16 (row = out col).
// grid (24, 64): blockIdx.x>>3 selects Q/K/V, &7 selects the 128-col tile.
// Q -> Qb * (scale*log2e); K -> Kb; V -> Vtb transposed [b][h][d][t].
__global__ __launch_bounds__(256, 2) void gemm_qkv(
    const unsigned short* __restrict__ A,
    const unsigned short* __restrict__ Wqkv,
    const float* __restrict__ bq, const float* __restrict__ bk,
    const float* __restrict__ bv,
    unsigned short* __restrict__ Qb, unsigned short* __restrict__ Kb,
    unsigned short* __restrict__ Vtb) {
  __shared__ __attribute__((aligned(16))) unsigned short As[128 * 64];
  __shared__ __attribute__((aligned(16))) unsigned short Bs[128 * 64];
  const int tid = threadIdx.x;
  const int wv = tid >> 6, lane = tid & 63;
  const int g = lane >> 4, rc = lane & 15;
  const int wr = wv >> 1, wc = wv & 1;
  const int nt = blockIdx.x >> 3;           // 0=Q 1=K 2=V
  const int n0 = (blockIdx.x & 7) * 128;    // within [0,1024)
  const int m0 = blockIdx.y * 128;
  const float* bias = (nt == 0) ? bq : (nt == 1) ? bk : bv;

  floatx4 acc[4][4] = {};
  const unsigned short* Ag = A + (size_t)m0 * 1024;
  const unsigned short* Wg = Wqkv + ((size_t)nt << 20) + (size_t)n0 * 1024;

  for (int kt = 0; kt < 16; ++kt) {
    stage128x64(Ag + kt * 64, 1024, As, tid);
    stage128x64(Wg + kt * 64, 1024, Bs, tid);
    __syncthreads();
    short8 af[4][2], bf[4][2];
#pragma unroll
    for (int m = 0; m < 4; ++m)
#pragma unroll
      for (int kk = 0; kk < 2; ++kk) {
        int row = wr * 64 + m * 16 + rc;
        int slot = (kk * 4 + g) ^ (row & 7);
        af[m][kk] = *reinterpret_cast<const short8*>(As + row * 64 + slot * 8);
      }
#pragma unroll
    for (int n = 0; n < 4; ++n)
#pragma unroll
      for (int kk = 0; kk < 2; ++kk) {
        int row = wc * 64 + n * 16 + rc;
        int slot = (kk * 4 + g) ^ (row & 7);
        bf[n][kk] = *reinterpret_cast<const short8*>(Bs + row * 64 + slot * 8);
      }
#pragma unroll
    for (int m = 0; m < 4; ++m)
#pragma unroll
      for (int n = 0; n < 4; ++n) {
        acc[m][n] = MFMA_BF16(af[m][0], bf[n][0], acc[m][n]);
        acc[m][n] = MFMA_BF16(af[m][1], bf[n][1], acc[m][n]);
      }
    __syncthreads();
  }

#pragma unroll
  for (int m = 0; m < 4; ++m) {
    const int gm = m0 + wr * 64 + m * 16 + g * 4;  // 4 consecutive output rows
#pragma unroll
    for (int n = 0; n < 4; ++n) {
      const int gn = n0 + wc * 64 + n * 16 + rc;   // within [0,1024)
      const float bs = bias[gn];
      floatx4 v = acc[m][n];
      if (nt == 2) {  // V: transpose to [b][h][d][t]
        const int bb = gm >> 11, t0 = gm & 2047;
        const int hh = gn >> 6, dd = gn & 63;
        ushortx4 p = {f2bf(v[0] + bs), f2bf(v[1] + bs), f2bf(v[2] + bs), f2bf(v[3] + bs)};
        *reinterpret_cast<ushortx4*>(Vtb + ((size_t)((bb * 16 + hh) * 64 + dd)) * 2048 + t0) = p;
      } else {
        unsigned short* O = (nt == 0) ? Qb : Kb;
        const float sc = (nt == 0) ? QK_SCALE_LOG2E : 1.0f;
#pragma unroll
        for (int i = 0; i < 4; ++i)
          O[(size_t)(gm + i) * 1024 + gn] = f2bf((v[i] + bs) * sc);
      }
    }
  }
}

// ---------------- out-projection GEMM (f32 output) ----------------
__global__ __launch_bounds__(256, 2) void gemm_out(
    const unsigned short* __restrict__ A,
    const unsigned short* __restrict__ W,
    const float* __restrict__ bias,
    float* __restrict__ out) {
  __shared__ __attribute__((aligned(16))) unsigned short As[128 * 64];
  __shared__ __attribute__((aligned(16))) unsigned short Bs[128 * 64];
  const int tid = threadIdx.x;
  const int wv = tid >> 6, lane = tid & 63;
  const int g = lane >> 4, rc = lane & 15;
  const int wr = wv >> 1, wc = wv & 1;
  const int m0 = blockIdx.y * 128, n0 = blockIdx.x * 128;

  floatx4 acc[4][4] = {};
  const unsigned short* Ag = A + (size_t)m0 * 1024;
  const unsigned short* Wg = W + (size_t)n0 * 1024;

  for (int kt = 0; kt < 16; ++kt) {
    stage128x64(Ag + kt * 64, 1024, As, tid);
    stage128x64(Wg + kt * 64, 1024, Bs, tid);
    __syncthreads();
    short8 af[4][2], bf[4][2];
#pragma unroll
    for (int m = 0; m < 4; ++m)
#pragma unroll
      for (int kk = 0; kk < 2; ++kk) {
        int row = wr * 64 + m * 16 + rc;
        int slot = (kk * 4 + g) ^ (row & 7);
        af[m][kk] = *reinterpret_cast<const short8*>(As + row * 64 + slot * 8);
      }
#pragma unroll
    for (int n = 0; n < 4; ++n)
#pragma unroll
      for (int kk = 0; kk < 2; ++kk) {
        int row = wc * 64 + n * 16 + rc;
        int slot = (kk * 4 + g) ^ (row & 7);
        bf[n][kk] = *reinterpret_cast<const short8*>(Bs + row * 64 + slot * 8);
      }
#pragma unroll
    for (int m = 0; m < 4; ++m)
#pragma unroll
      for (int n = 0; n < 4; ++n) {
        acc[m][n] = MFMA_BF16(af[m][0], bf[n][0], acc[m][n]);
        acc[m][n] = MFMA_BF16(af[m][1], bf[n][1], acc[m][n]);
      }
    __syncthreads();
  }

#pragma unroll
  for (int m = 0; m < 4; ++m) {
    const int gm = m0 + wr * 64 + m * 16 + g * 4;
#pragma unroll
    for (int n = 0; n < 4; ++n) {
      const int gn = n0 + wc * 64 + n * 16 + rc;
      const float bs = bias[gn];
#pragma unroll
      for (int i = 0; i < 4; ++i) out[(size_t)(gm + i) * 1024 + gn] = acc[m][n][i] + bs;
    }
  }
}

// ---------------- flash attention, swapped-operand (S^T), no-max softmax ----
// R4 geometry (QBLK=32/wave, 4 waves, 1024 blocks, XCD-local bh mapping) +
// 3-buffer depth-2 prefetch with COUNTED vmcnt (T4): per tile
//   s_waitcnt vmcnt(4) ; s_barrier ; issue loads for t+2 ; compute t
// -> tile t+1's 4 loads/thread stay in flight across the barrier (never
// drain to 0 in the loop). Staging t+2 overwrites tile t-1's buffer, safe:
// barrier(t) implies every wave finished compute(t-1).
// Scores in log2 domain (Q pre-scaled by scale*log2e) -> exp2 direct, no max.
// S^T = mfma(A=K, B=Q) with tau row permutation so the C-layout coincides
// with the PV B-operand layout. Row sums l = ones-row MFMA (A=1 at rc==0).
__global__ __launch_bounds__(256, 3) void attn_fwd(
    const unsigned short* __restrict__ Q,
    const unsigned short* __restrict__ K,
    const unsigned short* __restrict__ Vt,
    unsigned short* __restrict__ ctx) {
  __shared__ __attribute__((aligned(16))) unsigned short Ks0[64 * 64];
  __shared__ __attribute__((aligned(16))) unsigned short Ks1[64 * 64];
  __shared__ __attribute__((aligned(16))) unsigned short Ks2[64 * 64];
  __shared__ __attribute__((aligned(16))) unsigned short Vs0[64 * 64];
  __shared__ __attribute__((aligned(16))) unsigned short Vs1[64 * 64];
  __shared__ __attribute__((aligned(16))) unsigned short Vs2[64 * 64];
  const int tid = threadIdx.x;
  const int wv = tid >> 6, lane = tid & 63;
  const int g = lane >> 4, rc = lane & 15;
  const int f = blockIdx.x;
  const int i_ = f >> 3;
  const int bh = (f & 7) * 8 + (i_ & 7);   // f&7 = XCD; 8 bh per XCD (4MB = L2)
  const int qb = i_ >> 3;                  // [0,16)
  const int b = bh >> 4, h = bh & 15;
  const int q0 = qb * 128 + wv * 32;

  // Q fragments direct from global: row q0+q_*16+rc, col h*64 + kk*32 + g*8
  short8 qfr[2][2];
  {
    const unsigned short* Qg = Q + (size_t)(b * 2048 + q0 + rc) * 1024 + h * 64 + g * 8;
#pragma unroll
    for (int q_ = 0; q_ < 2; ++q_)
#pragma unroll
      for (int kk = 0; kk < 2; ++kk)
        qfr[q_][kk] = *reinterpret_cast<const short8*>(Qg + q_ * 16 * 1024 + kk * 32);
  }

  const unsigned short* Kg = K + (size_t)b * 2048 * 1024 + h * 64;
  const unsigned short* Vg = Vt + (size_t)bh * 64 * 2048;

  // lane-constant LDS byte offsets
  const int i4 = rc & 3, g4 = rc >> 2;
  const int kmask = i4 | ((g4 & 1) << 2);                        // mask of row tau(nf,m)
  const int koff0 = ((g4 * 8 + i4) * 64 + ((g)     ^ kmask) * 8) * 2;  // kk=0
  const int koff1 = ((g4 * 8 + i4) * 64 + ((4 + g) ^ kmask) * 8) * 2;  // kk=1
  const int vmask = rc & 7;
  const int voff0 = (rc * 64 + ((g)     ^ vmask) * 8) * 2;  // kb=0
  const int voff1 = (rc * 64 + ((4 + g) ^ vmask) * 8) * 2;  // kb=1

  // ones-row A fragment for the l-sum MFMA: A[0][k]=1, rows 1..15 = 0
  const int one2 = 0x3F803F80;  // two bf16 1.0
  intx4 ones_i = (rc == 0) ? intx4{one2, one2, one2, one2} : intx4{0, 0, 0, 0};
  const short8 vf_ones = __builtin_bit_cast(short8, ones_i);

  floatx4 acc[2][4] = {};
  floatx4 acc5[2] = {};  // row 0 accumulates l = sum_k P

  auto tile_compute = [&](const unsigned short* KsB, const unsigned short* VsB) {
    // S^T: rows = permuted k (64), cols = q (32 as 2 frags); K frags shared
    floatx4 sv[2][4] = {};
    __builtin_amdgcn_s_setprio(1);
#pragma unroll
    for (int nf = 0; nf < 4; ++nf) {
      const int ro = ((nf >> 1) * 32 + (nf & 1) * 4) * 128;  // row-group byte offset
      short8 kf0 = *reinterpret_cast<const short8*>((const char*)KsB + ro + koff0);
      short8 kf1 = *reinterpret_cast<const short8*>((const char*)KsB + ro + koff1);
      sv[0][nf] = MFMA_BF16(kf0, qfr[0][0], sv[0][nf]);
      sv[0][nf] = MFMA_BF16(kf1, qfr[0][1], sv[0][nf]);
      sv[1][nf] = MFMA_BF16(kf0, qfr[1][0], sv[1][nf]);
      sv[1][nf] = MFMA_BF16(kf1, qfr[1][1], sv[1][nf]);
    }
    __builtin_amdgcn_s_setprio(0);

    // softmax numerator: P = exp2(S) directly (no max tracking)
#pragma unroll
    for (int q_ = 0; q_ < 2; ++q_)
#pragma unroll
      for (int nf = 0; nf < 4; ++nf)
#pragma unroll
        for (int i = 0; i < 4; ++i)
          sv[q_][nf][i] = __builtin_amdgcn_exp2f(sv[q_][nf][i]);

    // PV: ctx^T += V^T P^T ; P packs straight from sv registers (tau-aligned);
    // 5th output row-block via vf_ones accumulates l.
#pragma unroll
    for (int kb = 0; kb < 2; ++kb) {
      intx4 w0, w1;
#pragma unroll
      for (int w = 0; w < 4; ++w) {
        const int nf = 2 * kb + (w >> 1), ii = (w & 1) * 2;
        w0[w] = cvt_pk_bf16(sv[0][nf][ii], sv[0][nf][ii + 1]);
        w1[w] = cvt_pk_bf16(sv[1][nf][ii], sv[1][nf][ii + 1]);
      }
      short8 pb0 = __builtin_bit_cast(short8, w0);
      short8 pb1 = __builtin_bit_cast(short8, w1);
      const int vo = kb ? voff1 : voff0;
      __builtin_amdgcn_s_setprio(1);
#pragma unroll
      for (int nd = 0; nd < 4; ++nd) {
        short8 vf = *reinterpret_cast<const short8*>((const char*)VsB + nd * 2048 + vo);
        acc[0][nd] = MFMA_BF16(vf, pb0, acc[0][nd]);
        acc[1][nd] = MFMA_BF16(vf, pb1, acc[1][nd]);
      }
      acc5[0] = MFMA_BF16(vf_ones, pb0, acc5[0]);
      acc5[1] = MFMA_BF16(vf_ones, pb1, acc5[1]);
      __builtin_amdgcn_s_setprio(0);
    }
  };

  // rotating buffer pointers (uniform -> SGPRs, no scratch)
  const unsigned short *K0 = Ks0, *K1 = Ks1, *K2 = Ks2;
  const unsigned short *V0 = Vs0, *V1 = Vs1, *V2 = Vs2;

  // prologue: stage tiles 0 and 1 (8 outstanding loads/thread)
  stage64x64<1>(Kg, 1024, (unsigned short*)K0, tid);
  stage64x64<0>(Vg, 2048, (unsigned short*)V0, tid);
  stage64x64<1>(Kg + (size_t)64 * 1024, 1024, (unsigned short*)K1, tid);
  stage64x64<0>(Vg + 64, 2048, (unsigned short*)V1, tid);

  for (int t = 0; t < 32; ++t) {
    // wait for tile t's 4 loads (leave t+1's 4 in flight), then publish
    if (t < 31) {
      asm volatile("s_waitcnt vmcnt(4)" ::: "memory");
    } else {
      asm volatile("s_waitcnt vmcnt(0)" ::: "memory");
    }
    __builtin_amdgcn_s_barrier();
    __builtin_amdgcn_sched_barrier(0);
    // prefetch tile t+2 into the buffer freed by tile t-1
    if (t + 2 < 32) {
      stage64x64<1>(Kg + (size_t)(t + 2) * 64 * 1024, 1024, (unsigned short*)K2, tid);
      stage64x64<0>(Vg + (t + 2) * 64, 2048, (unsigned short*)V2, tid);
    }
    tile_compute(K0, V0);
    // rotate
    const unsigned short* kt_ = K0; K0 = K1; K1 = K2; K2 = kt_;
    const unsigned short* vt_ = V0; V0 = V1; V1 = V2; V2 = vt_;
  }

  // epilogue: acc is ctx^T (rows d = nd*16+g*4+i, cols q = q_*16+rc);
  // l for col q lives in lane q, reg 0 of acc5 (C row 0).
#pragma unroll
  for (int q_ = 0; q_ < 2; ++q_) {
    const float l = __shfl(acc5[q_][0], rc);
    const float inv = 1.0f / l;
    unsigned short* Cp = ctx + (size_t)(b * 2048 + q0 + q_ * 16 + rc) * 1024 + h * 64 + g * 4;
#pragma unroll
    for (int nd = 0; nd < 4; ++nd) {
      ushortx4 o = {f2bf(acc[q_][nd][0] * inv), f2bf(acc[q_][nd][1] * inv),
                    f2bf(acc[q_][nd][2] * inv), f2bf(acc[q_][nd][3] * inv)};
      *reinterpret_cast<ushortx4*>(Cp + nd * 16) = o;
    }
  }
}

extern "C" void kernel_launch(void* const* d_in, const int* in_sizes, int n_in,
                              void* d_out, int out_size, void* d_ws, size_t ws_size,
                              hipStream_t stream) {
  (void)in_sizes; (void)n_in; (void)out_size; (void)ws_size;
  const float* x  = (const float*)d_in[0];
  const float* Wq = (const float*)d_in[1];
  const float* bq = (const float*)d_in[2];
  const float* Wk = (const float*)d_in[3];
  const float* bk = (const float*)d_in[4];
  const float* Wv = (const float*)d_in[5];
  const float* bv = (const float*)d_in[6];
  const float* Wo = (const float*)d_in[7];
  const float* bo = (const float*)d_in[8];

  // workspace layout (42 MB): Xb | Wqb Wkb Wvb Wob (contiguous) | Vtb ; ctx aliases Xb
  unsigned short* Xb  = (unsigned short*)d_ws;
  unsigned short* Wqb = Xb + (size_t)8192 * 1024;   // 3 QKV weights contiguous
  unsigned short* Wob = Wqb + (size_t)3 * 1024 * 1024;
  unsigned short* Vtb = Wob + (size_t)1024 * 1024;
  unsigned short* Ctx = Xb;  // X no longer needed once Q/K/V are materialized
  // Q,K (bf16) live in d_out (exactly 2 x 16.8MB = out bytes), overwritten by final GEMM
  unsigned short* Qb = (unsigned short*)d_out;
  unsigned short* Kb = Qb + (size_t)8192 * 1024;

  cvt_f32_bf16<<<8192, 256, 0, stream>>>(x, Xb, 8192 * 1024 / 4);
  cvt_w4<<<4096, 256, 0, stream>>>(Wq, Wk, Wv, Wo, Wqb);

  gemm_qkv<<<dim3(24, 64), 256, 0, stream>>>(Xb, Wqb, bq, bk, bv, Qb, Kb, Vtb);
  attn_fwd<<<1024, 256, 0, stream>>>(Qb, Kb, Vtb, Ctx);
  gemm_out<<<dim3(8, 64), 256, 0, stream>>>(Ctx, Wob, bo, (float*)d_out);
}

// Round 7
// 158.098 us; speedup vs baseline: 1.0470x; 1.0470x over previous
//
#include <hip/hip_runtime.h>
#include <cstdint>

#define DEV __device__ __forceinline__

using short8   = __attribute__((ext_vector_type(8))) short;
using floatx4  = __attribute__((ext_vector_type(4))) float;
using ushortx4 = __attribute__((ext_vector_type(4))) unsigned short;
using intx4    = __attribute__((ext_vector_type(4))) int;

#define MFMA_BF16(a, b, c) __builtin_amdgcn_mfma_f32_16x16x32_bf16((a), (b), (c), 0, 0, 0)

// 1/sqrt(64) * log2(e): fold softmax scale + exp2 conversion into Q
static constexpr float QK_SCALE_LOG2E = 0.18033688011112042f;

DEV unsigned short f2bf(float f) {
  unsigned int u = __builtin_bit_cast(unsigned int, f);
  u += 0x7FFFu + ((u >> 16) & 1u);  // RNE
  return (unsigned short)(u >> 16);
}

DEV int cvt_pk_bf16(float lo, float hi) {
  int r;
  asm("v_cvt_pk_bf16_f32 %0, %1, %2" : "=v"(r) : "v"(lo), "v"(hi));
  return r;
}

DEV void gload_lds16(const void* g, void* l) {
  __builtin_amdgcn_global_load_lds(
      (const __attribute__((address_space(1))) void*)g,
      (__attribute__((address_space(3))) void*)l, 16, 0, 0);
}

// ---------------- fp32 -> bf16 bulk converts ----------------
__global__ void cvt_f32_bf16(const float* __restrict__ src,
                             unsigned short* __restrict__ dst, int n4) {
  int i = blockIdx.x * blockDim.x + threadIdx.x;
  if (i >= n4) return;
  float4 v = reinterpret_cast<const float4*>(src)[i];
  ushortx4 o = {f2bf(v.x), f2bf(v.y), f2bf(v.z), f2bf(v.w)};
  reinterpret_cast<ushortx4*>(dst)[i] = o;
}

// 4 weight matrices (1024x1024 f32 each) -> contiguous bf16 dst
__global__ void cvt_w4(const float* __restrict__ w0, const float* __restrict__ w1,
                       const float* __restrict__ w2, const float* __restrict__ w3,
                       unsigned short* __restrict__ dst) {
  int i = blockIdx.x * blockDim.x + threadIdx.x;  // [0, 4*262144) float4 units
  int b = i >> 18;                                 // wave-uniform (256K per buffer)
  const float* src = (b == 0) ? w0 : (b == 1) ? w1 : (b == 2) ? w2 : w3;
  int off = i & 0x3FFFF;
  float4 v = reinterpret_cast<const float4*>(src)[off];
  ushortx4 o = {f2bf(v.x), f2bf(v.y), f2bf(v.z), f2bf(v.w)};
  reinterpret_cast<ushortx4*>(dst)[i] = o;
}

// ---- staging: global -> LDS, linear LDS dest, swizzle applied on SOURCE ----
// 128 rows x 64 bf16 cols (128B rows, 8x16B chunks), swizzle chunk^(row&7)
DEV void stage128x64(const unsigned short* gbase, int ld, unsigned short* lds, int tid) {
#pragma unroll
  for (int j = 0; j < 4; ++j) {
    int s = j * 256 + tid;
    int row = s >> 3, slot = s & 7;
    int chunk = slot ^ (row & 7);
    gload_lds16(gbase + row * ld + chunk * 8, (char*)lds + s * 16);
  }
}

// 64 rows x 64 bf16 cols, 512-thread block (1 load/thread).
// KMODE 1: mask=(row&3)|((row>>1)&4) (K tile, matches tau-permuted fragment
// reads); KMODE 0: mask=row&7 (V tile, consecutive rows).
template <int KMODE>
DEV void stage64x64_8w(const unsigned short* gbase, int ld, unsigned short* lds, int tid) {
  int row = tid >> 3, slot = tid & 7;
  int mask = KMODE ? ((row & 3) | ((row >> 1) & 4)) : (row & 7);
  int chunk = slot ^ mask;
  gload_lds16(gbase + row * ld + chunk * 8, (char*)lds + tid * 16);
}

// ---------------- fused QKV GEMM ----------------
// A [8192][1024] bf16, Wqkv = 3 contiguous [1024][1024] bf16 (row = out col).
// grid (24, 64): blockIdx.x>>3 selects Q/K/V, &7 selects the 128-col tile.
// Q -> Qb * (scale*log2e); K -> Kb; V -> Vtb transposed [b][h][d][t].
__global__ __launch_bounds__(256, 2) void gemm_qkv(
    const unsigned short* __restrict__ A,
    const unsigned short* __restrict__ Wqkv,
    const float* __restrict__ bq, const float* __restrict__ bk,
    const float* __restrict__ bv,
    unsigned short* __restrict__ Qb, unsigned short* __restrict__ Kb,
    unsigned short* __restrict__ Vtb) {
  __shared__ __attribute__((aligned(16))) unsigned short As[128 * 64];
  __shared__ __attribute__((aligned(16))) unsigned short Bs[128 * 64];
  const int tid = threadIdx.x;
  const int wv = tid >> 6, lane = tid & 63;
  const int g = lane >> 4, rc = lane & 15;
  const int wr = wv >> 1, wc = wv & 1;
  const int nt = blockIdx.x >> 3;           // 0=Q 1=K 2=V
  const int n0 = (blockIdx.x & 7) * 128;    // within [0,1024)
  const int m0 = blockIdx.y * 128;
  const float* bias = (nt == 0) ? bq : (nt == 1) ? bk : bv;

  floatx4 acc[4][4] = {};
  const unsigned short* Ag = A + (size_t)m0 * 1024;
  const unsigned short* Wg = Wqkv + ((size_t)nt << 20) + (size_t)n0 * 1024;

  for (int kt = 0; kt < 16; ++kt) {
    stage128x64(Ag + kt * 64, 1024, As, tid);
    stage128x64(Wg + kt * 64, 1024, Bs, tid);
    __syncthreads();
    short8 af[4][2], bf[4][2];
#pragma unroll
    for (int m = 0; m < 4; ++m)
#pragma unroll
      for (int kk = 0; kk < 2; ++kk) {
        int row = wr * 64 + m * 16 + rc;
        int slot = (kk * 4 + g) ^ (row & 7);
        af[m][kk] = *reinterpret_cast<const short8*>(As + row * 64 + slot * 8);
      }
#pragma unroll
    for (int n = 0; n < 4; ++n)
#pragma unroll
      for (int kk = 0; kk < 2; ++kk) {
        int row = wc * 64 + n * 16 + rc;
        int slot = (kk * 4 + g) ^ (row & 7);
        bf[n][kk] = *reinterpret_cast<const short8*>(Bs + row * 64 + slot * 8);
      }
#pragma unroll
    for (int m = 0; m < 4; ++m)
#pragma unroll
      for (int n = 0; n < 4; ++n) {
        acc[m][n] = MFMA_BF16(af[m][0], bf[n][0], acc[m][n]);
        acc[m][n] = MFMA_BF16(af[m][1], bf[n][1], acc[m][n]);
      }
    __syncthreads();
  }

#pragma unroll
  for (int m = 0; m < 4; ++m) {
    const int gm = m0 + wr * 64 + m * 16 + g * 4;  // 4 consecutive output rows
#pragma unroll
    for (int n = 0; n < 4; ++n) {
      const int gn = n0 + wc * 64 + n * 16 + rc;   // within [0,1024)
      const float bs = bias[gn];
      floatx4 v = acc[m][n];
      if (nt == 2) {  // V: transpose to [b][h][d][t]
        const int bb = gm >> 11, t0 = gm & 2047;
        const int hh = gn >> 6, dd = gn & 63;
        ushortx4 p = {f2bf(v[0] + bs), f2bf(v[1] + bs), f2bf(v[2] + bs), f2bf(v[3] + bs)};
        *reinterpret_cast<ushortx4*>(Vtb + ((size_t)((bb * 16 + hh) * 64 + dd)) * 2048 + t0) = p;
      } else {
        unsigned short* O = (nt == 0) ? Qb : Kb;
        const float sc = (nt == 0) ? QK_SCALE_LOG2E : 1.0f;
#pragma unroll
        for (int i = 0; i < 4; ++i)
          O[(size_t)(gm + i) * 1024 + gn] = f2bf((v[i] + bs) * sc);
      }
    }
  }
}

// ---------------- out-projection GEMM (f32 output) ----------------
__global__ __launch_bounds__(256, 2) void gemm_out(
    const unsigned short* __restrict__ A,
    const unsigned short* __restrict__ W,
    const float* __restrict__ bias,
    float* __restrict__ out) {
  __shared__ __attribute__((aligned(16))) unsigned short As[128 * 64];
  __shared__ __attribute__((aligned(16))) unsigned short Bs[128 * 64];
  const int tid = threadIdx.x;
  const int wv = tid >> 6, lane = tid & 63;
  const int g = lane >> 4, rc = lane & 15;
  const int wr = wv >> 1, wc = wv & 1;
  const int m0 = blockIdx.y * 128, n0 = blockIdx.x * 128;

  floatx4 acc[4][4] = {};
  const unsigned short* Ag = A + (size_t)m0 * 1024;
  const unsigned short* Wg = W + (size_t)n0 * 1024;

  for (int kt = 0; kt < 16; ++kt) {
    stage128x64(Ag + kt * 64, 1024, As, tid);
    stage128x64(Wg + kt * 64, 1024, Bs, tid);
    __syncthreads();
    short8 af[4][2], bf[4][2];
#pragma unroll
    for (int m = 0; m < 4; ++m)
#pragma unroll
      for (int kk = 0; kk < 2; ++kk) {
        int row = wr * 64 + m * 16 + rc;
        int slot = (kk * 4 + g) ^ (row & 7);
        af[m][kk] = *reinterpret_cast<const short8*>(As + row * 64 + slot * 8);
      }
#pragma unroll
    for (int n = 0; n < 4; ++n)
#pragma unroll
      for (int kk = 0; kk < 2; ++kk) {
        int row = wc * 64 + n * 16 + rc;
        int slot = (kk * 4 + g) ^ (row & 7);
        bf[n][kk] = *reinterpret_cast<const short8*>(Bs + row * 64 + slot * 8);
      }
#pragma unroll
    for (int m = 0; m < 4; ++m)
#pragma unroll
      for (int n = 0; n < 4; ++n) {
        acc[m][n] = MFMA_BF16(af[m][0], bf[n][0], acc[m][n]);
        acc[m][n] = MFMA_BF16(af[m][1], bf[n][1], acc[m][n]);
      }
    __syncthreads();
  }

#pragma unroll
  for (int m = 0; m < 4; ++m) {
    const int gm = m0 + wr * 64 + m * 16 + g * 4;
#pragma unroll
    for (int n = 0; n < 4; ++n) {
      const int gn = n0 + wc * 64 + n * 16 + rc;
      const float bs = bias[gn];
#pragma unroll
      for (int i = 0; i < 4; ++i) out[(size_t)(gm + i) * 1024 + gn] = acc[m][n][i] + bs;
    }
  }
}

// ---------------- flash attention, swapped-operand (S^T), no-max softmax ----
// 8-wave blocks (512 thr), QBLK=32/wave -> 256 q-rows per block; 512 blocks =
// 2 blocks/CU x 8 waves = 16 waves/CU (occupancy was the R4-R6 limiter).
// R4's proven 2-buffer stage->compute->syncthreads structure (prefetch issued
// before compute; loads land during the ~600cy compute phase).
// f&7 = XCD owns 8 bh (K+V 4 MB = one XCD L2); i_=f>>3: bh_lo=i_&7, qb=i_>>3.
// Scores in log2 domain (Q pre-scaled by scale*log2e) -> exp2 direct, no max.
// S^T = mfma(A=K, B=Q) with tau row permutation so the C-layout coincides
// with the PV B-operand layout. Row sums l = ones-row MFMA (A=1 at rc==0).
__global__ __launch_bounds__(512, 4) void attn_fwd(
    const unsigned short* __restrict__ Q,
    const unsigned short* __restrict__ K,
    const unsigned short* __restrict__ Vt,
    unsigned short* __restrict__ ctx) {
  __shared__ __attribute__((aligned(16))) unsigned short Ks0[64 * 64];
  __shared__ __attribute__((aligned(16))) unsigned short Ks1[64 * 64];
  __shared__ __attribute__((aligned(16))) unsigned short Vs0[64 * 64];
  __shared__ __attribute__((aligned(16))) unsigned short Vs1[64 * 64];
  const int tid = threadIdx.x;
  const int wv = tid >> 6, lane = tid & 63;
  const int g = lane >> 4, rc = lane & 15;
  const int f = blockIdx.x;
  const int i_ = f >> 3;
  const int bh = (f & 7) * 8 + (i_ & 7);   // f&7 = XCD; 8 bh per XCD (4MB = L2)
  const int qb = i_ >> 3;                  // [0,8)
  const int b = bh >> 4, h = bh & 15;
  const int q0 = qb * 256 + wv * 32;

  // Q fragments direct from global: row q0+q_*16+rc, col h*64 + kk*32 + g*8
  short8 qfr[2][2];
  {
    const unsigned short* Qg = Q + (size_t)(b * 2048 + q0 + rc) * 1024 + h * 64 + g * 8;
#pragma unroll
    for (int q_ = 0; q_ < 2; ++q_)
#pragma unroll
      for (int kk = 0; kk < 2; ++kk)
        qfr[q_][kk] = *reinterpret_cast<const short8*>(Qg + q_ * 16 * 1024 + kk * 32);
  }

  const unsigned short* Kg = K + (size_t)b * 2048 * 1024 + h * 64;
  const unsigned short* Vg = Vt + (size_t)bh * 64 * 2048;

  // lane-constant LDS byte offsets
  const int i4 = rc & 3, g4 = rc >> 2;
  const int kmask = i4 | ((g4 & 1) << 2);                        // mask of row tau(nf,m)
  const int koff0 = ((g4 * 8 + i4) * 64 + ((g)     ^ kmask) * 8) * 2;  // kk=0
  const int koff1 = ((g4 * 8 + i4) * 64 + ((4 + g) ^ kmask) * 8) * 2;  // kk=1
  const int vmask = rc & 7;
  const int voff0 = (rc * 64 + ((g)     ^ vmask) * 8) * 2;  // kb=0
  const int voff1 = (rc * 64 + ((4 + g) ^ vmask) * 8) * 2;  // kb=1

  // ones-row A fragment for the l-sum MFMA: A[0][k]=1, rows 1..15 = 0
  const int one2 = 0x3F803F80;  // two bf16 1.0
  intx4 ones_i = (rc == 0) ? intx4{one2, one2, one2, one2} : intx4{0, 0, 0, 0};
  const short8 vf_ones = __builtin_bit_cast(short8, ones_i);

  floatx4 acc[2][4] = {};
  floatx4 acc5[2] = {};  // row 0 accumulates l = sum_k P

  auto tile_compute = [&](const unsigned short* KsB, const unsigned short* VsB) {
    // S^T: rows = permuted k (64), cols = q (32 as 2 frags); K frags shared
    floatx4 sv[2][4] = {};
    __builtin_amdgcn_s_setprio(1);
#pragma unroll
    for (int nf = 0; nf < 4; ++nf) {
      const int ro = ((nf >> 1) * 32 + (nf & 1) * 4) * 128;  // row-group byte offset
      short8 kf0 = *reinterpret_cast<const short8*>((const char*)KsB + ro + koff0);
      short8 kf1 = *reinterpret_cast<const short8*>((const char*)KsB + ro + koff1);
      sv[0][nf] = MFMA_BF16(kf0, qfr[0][0], sv[0][nf]);
      sv[0][nf] = MFMA_BF16(kf1, qfr[0][1], sv[0][nf]);
      sv[1][nf] = MFMA_BF16(kf0, qfr[1][0], sv[1][nf]);
      sv[1][nf] = MFMA_BF16(kf1, qfr[1][1], sv[1][nf]);
    }
    __builtin_amdgcn_s_setprio(0);

    // softmax numerator: P = exp2(S) directly (no max tracking)
#pragma unroll
    for (int q_ = 0; q_ < 2; ++q_)
#pragma unroll
      for (int nf = 0; nf < 4; ++nf)
#pragma unroll
        for (int i = 0; i < 4; ++i)
          sv[q_][nf][i] = __builtin_amdgcn_exp2f(sv[q_][nf][i]);

    // PV: ctx^T += V^T P^T ; P packs straight from sv registers (tau-aligned);
    // 5th output row-block via vf_ones accumulates l.
#pragma unroll
    for (int kb = 0; kb < 2; ++kb) {
      intx4 w0, w1;
#pragma unroll
      for (int w = 0; w < 4; ++w) {
        const int nf = 2 * kb + (w >> 1), ii = (w & 1) * 2;
        w0[w] = cvt_pk_bf16(sv[0][nf][ii], sv[0][nf][ii + 1]);
        w1[w] = cvt_pk_bf16(sv[1][nf][ii], sv[1][nf][ii + 1]);
      }
      short8 pb0 = __builtin_bit_cast(short8, w0);
      short8 pb1 = __builtin_bit_cast(short8, w1);
      const int vo = kb ? voff1 : voff0;
      __builtin_amdgcn_s_setprio(1);
#pragma unroll
      for (int nd = 0; nd < 4; ++nd) {
        short8 vf = *reinterpret_cast<const short8*>((const char*)VsB + nd * 2048 + vo);
        acc[0][nd] = MFMA_BF16(vf, pb0, acc[0][nd]);
        acc[1][nd] = MFMA_BF16(vf, pb1, acc[1][nd]);
      }
      acc5[0] = MFMA_BF16(vf_ones, pb0, acc5[0]);
      acc5[1] = MFMA_BF16(vf_ones, pb1, acc5[1]);
      __builtin_amdgcn_s_setprio(0);
    }
  };

  // prologue: stage tile 0, drain, barrier
  stage64x64_8w<1>(Kg, 1024, Ks0, tid);
  stage64x64_8w<0>(Vg, 2048, Vs0, tid);
  __syncthreads();

  for (int t = 0; t < 32; t += 2) {
    // prefetch tile t+1 into buf1, then compute tile t from buf0
    stage64x64_8w<1>(Kg + (size_t)(t + 1) * 64 * 1024, 1024, Ks1, tid);
    stage64x64_8w<0>(Vg + (t + 1) * 64, 2048, Vs1, tid);
    tile_compute(Ks0, Vs0);
    __syncthreads();  // tile t+1 landed; all waves done reading buf0
    // prefetch tile t+2 into buf0, then compute tile t+1 from buf1
    if (t + 2 < 32) {
      stage64x64_8w<1>(Kg + (size_t)(t + 2) * 64 * 1024, 1024, Ks0, tid);
      stage64x64_8w<0>(Vg + (t + 2) * 64, 2048, Vs0, tid);
    }
    tile_compute(Ks1, Vs1);
    __syncthreads();
  }

  // epilogue: acc is ctx^T (rows d = nd*16+g*4+i, cols q = q_*16+rc);
  // l for col q lives in lane q, reg 0 of acc5 (C row 0).
#pragma unroll
  for (int q_ = 0; q_ < 2; ++q_) {
    const float l = __shfl(acc5[q_][0], rc);
    const float inv = 1.0f / l;
    unsigned short* Cp = ctx + (size_t)(b * 2048 + q0 + q_ * 16 + rc) * 1024 + h * 64 + g * 4;
#pragma unroll
    for (int nd = 0; nd < 4; ++nd) {
      ushortx4 o = {f2bf(acc[q_][nd][0] * inv), f2bf(acc[q_][nd][1] * inv),
                    f2bf(acc[q_][nd][2] * inv), f2bf(acc[q_][nd][3] * inv)};
      *reinterpret_cast<ushortx4*>(Cp + nd * 16) = o;
    }
  }
}

extern "C" void kernel_launch(void* const* d_in, const int* in_sizes, int n_in,
                              void* d_out, int out_size, void* d_ws, size_t ws_size,
                              hipStream_t stream) {
  (void)in_sizes; (void)n_in; (void)out_size; (void)ws_size;
  const float* x  = (const float*)d_in[0];
  const float* Wq = (const float*)d_in[1];
  const float* bq = (const float*)d_in[2];
  const float* Wk = (const float*)d_in[3];
  const float* bk = (const float*)d_in[4];
  const float* Wv = (const float*)d_in[5];
  const float* bv = (const float*)d_in[6];
  const float* Wo = (const float*)d_in[7];
  const float* bo = (const float*)d_in[8];

  // workspace layout (42 MB): Xb | Wqb Wkb Wvb Wob (contiguous) | Vtb ; ctx aliases Xb
  unsigned short* Xb  = (unsigned short*)d_ws;
  unsigned short* Wqb = Xb + (size_t)8192 * 1024;   // 3 QKV weights contiguous
  unsigned short* Wob = Wqb + (size_t)3 * 1024 * 1024;
  unsigned short* Vtb = Wob + (size_t)1024 * 1024;
  unsigned short* Ctx = Xb;  // X no longer needed once Q/K/V are materialized
  // Q,K (bf16) live in d_out (exactly 2 x 16.8MB = out bytes), overwritten by final GEMM
  unsigned short* Qb = (unsigned short*)d_out;
  unsigned short* Kb = Qb + (size_t)8192 * 1024;

  cvt_f32_bf16<<<8192, 256, 0, stream>>>(x, Xb, 8192 * 1024 / 4);
  cvt_w4<<<4096, 256, 0, stream>>>(Wq, Wk, Wv, Wo, Wqb);

  gemm_qkv<<<dim3(24, 64), 256, 0, stream>>>(Xb, Wqb, bq, bk, bv, Qb, Kb, Vtb);
  attn_fwd<<<512, 512, 0, stream>>>(Qb, Kb, Vtb, Ctx);
  gemm_out<<<dim3(8, 64), 256, 0, stream>>>(Ctx, Wob, bo, (float*)d_out);
}

// Round 9
// 151.151 us; speedup vs baseline: 1.0951x; 1.0460x over previous
//
#include <hip/hip_runtime.h>
#include <cstdint>

#define DEV __device__ __forceinline__

using short8   = __attribute__((ext_vector_type(8))) short;
using floatx4  = __attribute__((ext_vector_type(4))) float;
using ushortx4 = __attribute__((ext_vector_type(4))) unsigned short;
using intx4    = __attribute__((ext_vector_type(4))) int;

#define MFMA_BF16(a, b, c) __builtin_amdgcn_mfma_f32_16x16x32_bf16((a), (b), (c), 0, 0, 0)

// 1/sqrt(64) * log2(e): fold softmax scale + exp2 conversion into Q
static constexpr float QK_SCALE_LOG2E = 0.18033688011112042f;

DEV unsigned short f2bf(float f) {
  unsigned int u = __builtin_bit_cast(unsigned int, f);
  u += 0x7FFFu + ((u >> 16) & 1u);  // RNE
  return (unsigned short)(u >> 16);
}

DEV int cvt_pk_bf16(float lo, float hi) {
  int r;
  asm("v_cvt_pk_bf16_f32 %0, %1, %2" : "=v"(r) : "v"(lo), "v"(hi));
  return r;
}

DEV void gload_lds16(const void* g, void* l) {
  __builtin_amdgcn_global_load_lds(
      (const __attribute__((address_space(1))) void*)g,
      (__attribute__((address_space(3))) void*)l, 16, 0, 0);
}

// ---------------- fp32 -> bf16 bulk convert (X + 4 weights, one launch) ----
__global__ void cvt_all(const float* __restrict__ x,
                        const float* __restrict__ w0, const float* __restrict__ w1,
                        const float* __restrict__ w2, const float* __restrict__ w3,
                        unsigned short* __restrict__ Xb,
                        unsigned short* __restrict__ Wb) {
  int i = blockIdx.x * blockDim.x + threadIdx.x;
  if (i < 2097152) {  // X: 8192*1024/4 float4 units
    float4 v = reinterpret_cast<const float4*>(x)[i];
    ushortx4 o = {f2bf(v.x), f2bf(v.y), f2bf(v.z), f2bf(v.w)};
    reinterpret_cast<ushortx4*>(Xb)[i] = o;
  } else {            // weights: 4 x 262144 float4 units, contiguous dst
    int j = i - 2097152;
    int b = j >> 18;  // wave-uniform (256K float4 per matrix)
    const float* src = (b == 0) ? w0 : (b == 1) ? w1 : (b == 2) ? w2 : w3;
    int off = j & 0x3FFFF;
    float4 v = reinterpret_cast<const float4*>(src)[off];
    ushortx4 o = {f2bf(v.x), f2bf(v.y), f2bf(v.z), f2bf(v.w)};
    reinterpret_cast<ushortx4*>(Wb)[j] = o;
  }
}

// ---- staging: global -> LDS, linear LDS dest, swizzle applied on SOURCE ----
// 128 rows x 64 bf16 cols (128B rows, 8x16B chunks), swizzle chunk^(row&7)
DEV void stage128x64(const unsigned short* gbase, int ld, unsigned short* lds, int tid) {
#pragma unroll
  for (int j = 0; j < 4; ++j) {
    int s = j * 256 + tid;
    int row = s >> 3, slot = s & 7;
    int chunk = slot ^ (row & 7);
    gload_lds16(gbase + row * ld + chunk * 8, (char*)lds + s * 16);
  }
}

// 64 rows x 64 bf16 cols, 512-thread block (1 load/thread).
// KMODE 1: mask=(row&3)|((row>>1)&4) (K tile, matches tau-permuted fragment
// reads); KMODE 0: mask=row&7 (V tile, consecutive rows).
template <int KMODE>
DEV void stage64x64_8w(const unsigned short* gbase, int ld, unsigned short* lds, int tid) {
  int row = tid >> 3, slot = tid & 7;
  int mask = KMODE ? ((row & 3) | ((row >> 1) & 4)) : (row & 7);
  int chunk = slot ^ mask;
  gload_lds16(gbase + row * ld + chunk * 8, (char*)lds + tid * 16);
}

// ---------------- fused QKV GEMM, XCD-chunked 1-D grid ----------------
// A [8192][1024] bf16, Wqkv = 3 contiguous [1024][1024] bf16 (row = out col).
// grid 1536 = 8 xcd x 8 m-local x 24 n-groups. id&7 = XCD (round-robin
// dispatch): each XCD owns m-tiles [xcd*8, xcd*8+8) -> its A-panel (2 MB)
// stays resident in that XCD's 4 MB L2; n-major ordering streams W through
// in ~2 MB slices. Q -> Qb * (scale*log2e); K -> Kb; V -> Vtb [b][h][d][t].
__global__ __launch_bounds__(256, 2) void gemm_qkv(
    const unsigned short* __restrict__ A,
    const unsigned short* __restrict__ Wqkv,
    const float* __restrict__ bq, const float* __restrict__ bk,
    const float* __restrict__ bv,
    unsigned short* __restrict__ Qb, unsigned short* __restrict__ Kb,
    unsigned short* __restrict__ Vtb) {
  __shared__ __attribute__((aligned(16))) unsigned short As[128 * 64];
  __shared__ __attribute__((aligned(16))) unsigned short Bs[128 * 64];
  const int tid = threadIdx.x;
  const int wv = tid >> 6, lane = tid & 63;
  const int g = lane >> 4, rc = lane & 15;
  const int wr = wv >> 1, wc = wv & 1;
  const int id = blockIdx.x;
  const int xcd = id & 7, c = id >> 3;
  const int mloc = c & 7, ng = c >> 3;      // ng in [0,24), n-major temporal
  const int nt = ng >> 3;                   // 0=Q 1=K 2=V
  const int n0 = (ng & 7) * 128;            // within [0,1024)
  const int m0 = (xcd * 8 + mloc) * 128;    // within [0,8192)
  const float* bias = (nt == 0) ? bq : (nt == 1) ? bk : bv;

  floatx4 acc[4][4] = {};
  const unsigned short* Ag = A + (size_t)m0 * 1024;
  const unsigned short* Wg = Wqkv + ((size_t)nt << 20) + (size_t)n0 * 1024;

  for (int kt = 0; kt < 16; ++kt) {
    stage128x64(Ag + kt * 64, 1024, As, tid);
    stage128x64(Wg + kt * 64, 1024, Bs, tid);
    __syncthreads();
    short8 af[4][2], bf[4][2];
#pragma unroll
    for (int m = 0; m < 4; ++m)
#pragma unroll
      for (int kk = 0; kk < 2; ++kk) {
        int row = wr * 64 + m * 16 + rc;
        int slot = (kk * 4 + g) ^ (row & 7);
        af[m][kk] = *reinterpret_cast<const short8*>(As + row * 64 + slot * 8);
      }
#pragma unroll
    for (int n = 0; n < 4; ++n)
#pragma unroll
      for (int kk = 0; kk < 2; ++kk) {
        int row = wc * 64 + n * 16 + rc;
        int slot = (kk * 4 + g) ^ (row & 7);
        bf[n][kk] = *reinterpret_cast<const short8*>(Bs + row * 64 + slot * 8);
      }
#pragma unroll
    for (int m = 0; m < 4; ++m)
#pragma unroll
      for (int n = 0; n < 4; ++n) {
        acc[m][n] = MFMA_BF16(af[m][0], bf[n][0], acc[m][n]);
        acc[m][n] = MFMA_BF16(af[m][1], bf[n][1], acc[m][n]);
      }
    __syncthreads();
  }

#pragma unroll
  for (int m = 0; m < 4; ++m) {
    const int gm = m0 + wr * 64 + m * 16 + g * 4;  // 4 consecutive output rows
#pragma unroll
    for (int n = 0; n < 4; ++n) {
      const int gn = n0 + wc * 64 + n * 16 + rc;   // within [0,1024)
      const float bs = bias[gn];
      floatx4 v = acc[m][n];
      if (nt == 2) {  // V: transpose to [b][h][d][t]
        const int bb = gm >> 11, t0 = gm & 2047;
        const int hh = gn >> 6, dd = gn & 63;
        ushortx4 p = {f2bf(v[0] + bs), f2bf(v[1] + bs), f2bf(v[2] + bs), f2bf(v[3] + bs)};
        *reinterpret_cast<ushortx4*>(Vtb + ((size_t)((bb * 16 + hh) * 64 + dd)) * 2048 + t0) = p;
      } else {
        unsigned short* O = (nt == 0) ? Qb : Kb;
        const float sc = (nt == 0) ? QK_SCALE_LOG2E : 1.0f;
#pragma unroll
        for (int i = 0; i < 4; ++i)
          O[(size_t)(gm + i) * 1024 + gn] = f2bf((v[i] + bs) * sc);
      }
    }
  }
}

// ---------------- out-projection GEMM (f32 output), XCD-chunked ------------
// grid 512 = 8 xcd x 8 m-local x 8 n; same L2-residency mapping as gemm_qkv.
__global__ __launch_bounds__(256, 2) void gemm_out(
    const unsigned short* __restrict__ A,
    const unsigned short* __restrict__ W,
    const float* __restrict__ bias,
    float* __restrict__ out) {
  __shared__ __attribute__((aligned(16))) unsigned short As[128 * 64];
  __shared__ __attribute__((aligned(16))) unsigned short Bs[128 * 64];
  const int tid = threadIdx.x;
  const int wv = tid >> 6, lane = tid & 63;
  const int g = lane >> 4, rc = lane & 15;
  const int wr = wv >> 1, wc = wv & 1;
  const int id = blockIdx.x;
  const int xcd = id & 7, c = id >> 3;
  const int mloc = c & 7, nx = c >> 3;      // nx in [0,8), n-major temporal
  const int m0 = (xcd * 8 + mloc) * 128;
  const int n0 = nx * 128;

  floatx4 acc[4][4] = {};
  const unsigned short* Ag = A + (size_t)m0 * 1024;
  const unsigned short* Wg = W + (size_t)n0 * 1024;

  for (int kt = 0; kt < 16; ++kt) {
    stage128x64(Ag + kt * 64, 1024, As, tid);
    stage128x64(Wg + kt * 64, 1024, Bs, tid);
    __syncthreads();
    short8 af[4][2], bf[4][2];
#pragma unroll
    for (int m = 0; m < 4; ++m)
#pragma unroll
      for (int kk = 0; kk < 2; ++kk) {
        int row = wr * 64 + m * 16 + rc;
        int slot = (kk * 4 + g) ^ (row & 7);
        af[m][kk] = *reinterpret_cast<const short8*>(As + row * 64 + slot * 8);
      }
#pragma unroll
    for (int n = 0; n < 4; ++n)
#pragma unroll
      for (int kk = 0; kk < 2; ++kk) {
        int row = wc * 64 + n * 16 + rc;
        int slot = (kk * 4 + g) ^ (row & 7);
        bf[n][kk] = *reinterpret_cast<const short8*>(Bs + row * 64 + slot * 8);
      }
#pragma unroll
    for (int m = 0; m < 4; ++m)
#pragma unroll
      for (int n = 0; n < 4; ++n) {
        acc[m][n] = MFMA_BF16(af[m][0], bf[n][0], acc[m][n]);
        acc[m][n] = MFMA_BF16(af[m][1], bf[n][1], acc[m][n]);
      }
    __syncthreads();
  }

#pragma unroll
  for (int m = 0; m < 4; ++m) {
    const int gm = m0 + wr * 64 + m * 16 + g * 4;
#pragma unroll
    for (int n = 0; n < 4; ++n) {
      const int gn = n0 + wc * 64 + n * 16 + rc;
      const float bs = bias[gn];
#pragma unroll
      for (int i = 0; i < 4; ++i) out[(size_t)(gm + i) * 1024 + gn] = acc[m][n][i] + bs;
    }
  }
}

// ---------------- flash attention, swapped-operand (S^T), no-max softmax ----
// EXACT R7 structure (proven): 8-wave blocks (512 thr), QBLK=32/wave, 512
// blocks -> 16 waves/CU; 2-buffer stage->compute->syncthreads.
// f&7 = XCD owns 8 bh (K+V 4 MB = one XCD L2); i_=f>>3: bh_lo=i_&7, qb=i_>>3.
// Scores in log2 domain (Q pre-scaled by scale*log2e) -> exp2 direct, no max.
// S^T = mfma(A=K, B=Q) with tau row permutation so the C-layout coincides
// with the PV B-operand layout. Row sums l = ones-row MFMA (A=1 at rc==0).
__global__ __launch_bounds__(512, 4) void attn_fwd(
    const unsigned short* __restrict__ Q,
    const unsigned short* __restrict__ K,
    const unsigned short* __restrict__ Vt,
    unsigned short* __restrict__ ctx) {
  __shared__ __attribute__((aligned(16))) unsigned short Ks0[64 * 64];
  __shared__ __attribute__((aligned(16))) unsigned short Ks1[64 * 64];
  __shared__ __attribute__((aligned(16))) unsigned short Vs0[64 * 64];
  __shared__ __attribute__((aligned(16))) unsigned short Vs1[64 * 64];
  const int tid = threadIdx.x;
  const int wv = tid >> 6, lane = tid & 63;
  const int g = lane >> 4, rc = lane & 15;
  const int f = blockIdx.x;
  const int i_ = f >> 3;
  const int bh = (f & 7) * 8 + (i_ & 7);   // f&7 = XCD; 8 bh per XCD (4MB = L2)
  const int qb = i_ >> 3;                  // [0,8)
  const int b = bh >> 4, h = bh & 15;
  const int q0 = qb * 256 + wv * 32;

  // Q fragments direct from global: row q0+q_*16+rc, col h*64 + kk*32 + g*8
  short8 qfr[2][2];
  {
    const unsigned short* Qg = Q + (size_t)(b * 2048 + q0 + rc) * 1024 + h * 64 + g * 8;
#pragma unroll
    for (int q_ = 0; q_ < 2; ++q_)
#pragma unroll
      for (int kk = 0; kk < 2; ++kk)
        qfr[q_][kk] = *reinterpret_cast<const short8*>(Qg + q_ * 16 * 1024 + kk * 32);
  }

  const unsigned short* Kg = K + (size_t)b * 2048 * 1024 + h * 64;
  const unsigned short* Vg = Vt + (size_t)bh * 64 * 2048;

  // lane-constant LDS byte offsets
  const int i4 = rc & 3, g4 = rc >> 2;
  const int kmask = i4 | ((g4 & 1) << 2);                        // mask of row tau(nf,m)
  const int koff0 = ((g4 * 8 + i4) * 64 + ((g)     ^ kmask) * 8) * 2;  // kk=0
  const int koff1 = ((g4 * 8 + i4) * 64 + ((4 + g) ^ kmask) * 8) * 2;  // kk=1
  const int vmask = rc & 7;
  const int voff0 = (rc * 64 + ((g)     ^ vmask) * 8) * 2;  // kb=0
  const int voff1 = (rc * 64 + ((4 + g) ^ vmask) * 8) * 2;  // kb=1

  // ones-row A fragment for the l-sum MFMA: A[0][k]=1, rows 1..15 = 0
  const int one2 = 0x3F803F80;  // two bf16 1.0
  intx4 ones_i = (rc == 0) ? intx4{one2, one2, one2, one2} : intx4{0, 0, 0, 0};
  const short8 vf_ones = __builtin_bit_cast(short8, ones_i);

  floatx4 acc[2][4] = {};
  floatx4 acc5[2] = {};  // row 0 accumulates l = sum_k P

  auto tile_compute = [&](const unsigned short* KsB, const unsigned short* VsB) {
    // S^T: rows = permuted k (64), cols = q (32 as 2 frags); K frags shared
    floatx4 sv[2][4] = {};
    __builtin_amdgcn_s_setprio(1);
#pragma unroll
    for (int nf = 0; nf < 4; ++nf) {
      const int ro = ((nf >> 1) * 32 + (nf & 1) * 4) * 128;  // row-group byte offset
      short8 kf0 = *reinterpret_cast<const short8*>((const char*)KsB + ro + koff0);
      short8 kf1 = *reinterpret_cast<const short8*>((const char*)KsB + ro + koff1);
      sv[0][nf] = MFMA_BF16(kf0, qfr[0][0], sv[0][nf]);
      sv[0][nf] = MFMA_BF16(kf1, qfr[0][1], sv[0][nf]);
      sv[1][nf] = MFMA_BF16(kf0, qfr[1][0], sv[1][nf]);
      sv[1][nf] = MFMA_BF16(kf1, qfr[1][1], sv[1][nf]);
    }
    __builtin_amdgcn_s_setprio(0);

    // softmax numerator: P = exp2(S) directly (no max tracking)
#pragma unroll
    for (int q_ = 0; q_ < 2; ++q_)
#pragma unroll
      for (int nf = 0; nf < 4; ++nf)
#pragma unroll
        for (int i = 0; i < 4; ++i)
          sv[q_][nf][i] = __builtin_amdgcn_exp2f(sv[q_][nf][i]);

    // PV: ctx^T += V^T P^T ; P packs straight from sv registers (tau-aligned);
    // 5th output row-block via vf_ones accumulates l.
#pragma unroll
    for (int kb = 0; kb < 2; ++kb) {
      intx4 w0, w1;
#pragma unroll
      for (int w = 0; w < 4; ++w) {
        const int nf = 2 * kb + (w >> 1), ii = (w & 1) * 2;
        w0[w] = cvt_pk_bf16(sv[0][nf][ii], sv[0][nf][ii + 1]);
        w1[w] = cvt_pk_bf16(sv[1][nf][ii], sv[1][nf][ii + 1]);
      }
      short8 pb0 = __builtin_bit_cast(short8, w0);
      short8 pb1 = __builtin_bit_cast(short8, w1);
      const int vo = kb ? voff1 : voff0;
      __builtin_amdgcn_s_setprio(1);
#pragma unroll
      for (int nd = 0; nd < 4; ++nd) {
        short8 vf = *reinterpret_cast<const short8*>((const char*)VsB + nd * 2048 + vo);
        acc[0][nd] = MFMA_BF16(vf, pb0, acc[0][nd]);
        acc[1][nd] = MFMA_BF16(vf, pb1, acc[1][nd]);
      }
      acc5[0] = MFMA_BF16(vf_ones, pb0, acc5[0]);
      acc5[1] = MFMA_BF16(vf_ones, pb1, acc5[1]);
      __builtin_amdgcn_s_setprio(0);
    }
  };

  // prologue: stage tile 0, drain, barrier
  stage64x64_8w<1>(Kg, 1024, Ks0, tid);
  stage64x64_8w<0>(Vg, 2048, Vs0, tid);
  __syncthreads();

  for (int t = 0; t < 32; t += 2) {
    // prefetch tile t+1 into buf1, then compute tile t from buf0
    stage64x64_8w<1>(Kg + (size_t)(t + 1) * 64 * 1024, 1024, Ks1, tid);
    stage64x64_8w<0>(Vg + (t + 1) * 64, 2048, Vs1, tid);
    tile_compute(Ks0, Vs0);
    __syncthreads();  // tile t+1 landed; all waves done reading buf0
    // prefetch tile t+2 into buf0, then compute tile t+1 from buf1
    if (t + 2 < 32) {
      stage64x64_8w<1>(Kg + (size_t)(t + 2) * 64 * 1024, 1024, Ks0, tid);
      stage64x64_8w<0>(Vg + (t + 2) * 64, 2048, Vs0, tid);
    }
    tile_compute(Ks1, Vs1);
    __syncthreads();
  }

  // epilogue: acc is ctx^T (rows d = nd*16+g*4+i, cols q = q_*16+rc);
  // l for col q lives in lane q, reg 0 of acc5 (C row 0).
#pragma unroll
  for (int q_ = 0; q_ < 2; ++q_) {
    const float l = __shfl(acc5[q_][0], rc);
    const float inv = 1.0f / l;
    unsigned short* Cp = ctx + (size_t)(b * 2048 + q0 + q_ * 16 + rc) * 1024 + h * 64 + g * 4;
#pragma unroll
    for (int nd = 0; nd < 4; ++nd) {
      ushortx4 o = {f2bf(acc[q_][nd][0] * inv), f2bf(acc[q_][nd][1] * inv),
                    f2bf(acc[q_][nd][2] * inv), f2bf(acc[q_][nd][3] * inv)};
      *reinterpret_cast<ushortx4*>(Cp + nd * 16) = o;
    }
  }
}

extern "C" void kernel_launch(void* const* d_in, const int* in_sizes, int n_in,
                              void* d_out, int out_size, void* d_ws, size_t ws_size,
                              hipStream_t stream) {
  (void)in_sizes; (void)n_in; (void)out_size; (void)ws_size;
  const float* x  = (const float*)d_in[0];
  const float* Wq = (const float*)d_in[1];
  const float* bq = (const float*)d_in[2];
  const float* Wk = (const float*)d_in[3];
  const float* bk = (const float*)d_in[4];
  const float* Wv = (const float*)d_in[5];
  const float* bv = (const float*)d_in[6];
  const float* Wo = (const float*)d_in[7];
  const float* bo = (const float*)d_in[8];

  // workspace layout (42 MB): Xb | Wqb Wkb Wvb Wob (contiguous) | Vtb ; ctx aliases Xb
  unsigned short* Xb  = (unsigned short*)d_ws;
  unsigned short* Wqb = Xb + (size_t)8192 * 1024;   // 3 QKV weights contiguous
  unsigned short* Wob = Wqb + (size_t)3 * 1024 * 1024;
  unsigned short* Vtb = Wob + (size_t)1024 * 1024;
  unsigned short* Ctx = Xb;  // X no longer needed once Q/K/V are materialized
  // Q,K (bf16) live in d_out (exactly 2 x 16.8MB = out bytes), overwritten by final GEMM
  unsigned short* Qb = (unsigned short*)d_out;
  unsigned short* Kb = Qb + (size_t)8192 * 1024;

  cvt_all<<<12288, 256, 0, stream>>>(x, Wq, Wk, Wv, Wo, Xb, Wqb);

  gemm_qkv<<<1536, 256, 0, stream>>>(Xb, Wqb, bq, bk, bv, Qb, Kb, Vtb);
  attn_fwd<<<512, 512, 0, stream>>>(Qb, Kb, Vtb, Ctx);
  gemm_out<<<512, 256, 0, stream>>>(Ctx, Wob, bo, (float*)d_out);
}